// Round 4
// baseline (276.881 us; speedup 1.0000x reference)
//
#include <hip/hip_runtime.h>
#include <hip/hip_cooperative_groups.h>

namespace cg = cooperative_groups;

#define NIMG 8
#define IMH 2048
#define IMW 2048
#define GH 8
#define GW 8
#define NBINS 256
#define NTPI 64                        // tiles per image
#define CLIP_MAXF 256.0f               // clip_limit*pixels//NBINS = 65536//256
#define LUT_SCALE 0.0038909912109375f  // 255/65536, exact in f32
#define LOG_GAIN_F 2.5f

#define FUSED_BLOCKS 512               // one block per 256x256 tile
#define MM_BLOCKS 2048                 // fallback k_minmax_in grid

__device__ __forceinline__ int pix_bin(float v, float mn, float den) {
    float xn = (v - mn) / den;
    float t  = LOG_GAIN_F * log2f(1.0f + xn);
    float xc = fminf(fmaxf(t, 0.0f), 1.0f);
    int b = (int)(xc * 256.0f);
    return min(max(b, 0), 255);
}

__device__ __forceinline__ void mm4(float4 v, float& mn, float& mx) {
    mn = fminf(mn, fminf(fminf(v.x, v.y), fminf(v.z, v.w)));
    mx = fmaxf(mx, fmaxf(fmaxf(v.x, v.y), fmaxf(v.z, v.w)));
}

// block min/max; result broadcast to ALL threads. Safe to call repeatedly
// (leading __syncthreads protects the shared scratch).
template <int NWAVES>
__device__ __forceinline__ void block_minmax_all(float& mn, float& mx, int t) {
    __shared__ float smn[NWAVES], smx[NWAVES];
    __syncthreads();
#pragma unroll
    for (int m = 32; m >= 1; m >>= 1) {
        mn = fminf(mn, __shfl_xor(mn, m, 64));
        mx = fmaxf(mx, __shfl_xor(mx, m, 64));
    }
    int wid = t >> 6, lid = t & 63;
    if (lid == 0) { smn[wid] = mn; smx[wid] = mx; }
    __syncthreads();
    mn = smn[0]; mx = smx[0];
#pragma unroll
    for (int i = 1; i < NWAVES; i++) { mn = fminf(mn, smn[i]); mx = fmaxf(mx, smx[i]); }
}

// load the 4 neighboring-tile LUTs for quadrant (qy,qx) into L[4][256]
__device__ __forceinline__ void load_L(const float* __restrict__ lb, int qy, int qx,
                                       float (*L)[NBINS], int t) {
    int ty = qy >> 1, tx = qx >> 1;
    int yA = (qy & 1) ? ty : max(ty - 1, 0);
    int yB = (qy & 1) ? min(ty + 1, GH - 1) : ty;
    int xA = (qx & 1) ? tx : max(tx - 1, 0);
    int xB = (qx & 1) ? min(tx + 1, GW - 1) : tx;
    int ci = t & 255;
#pragma unroll
    for (int j = 0; j < 2; ++j) {
        int which = (t >> 8) + 2 * j;   // 0..3 across 512 threads x 2 iters
        int yy = (which >= 2) ? yB : yA;
        int xx = (which & 1) ? xB : xA;
        L[which][ci] = lb[(size_t)(yy * GW + xx) * NBINS + ci];
    }
}

// ===================== fused cooperative kernel =====================
// 512 blocks x 512 threads, one block per 256x256 tile. Per-pixel bins live
// in LDS for the whole kernel; only LUTs (4KB/tile) cross blocks via global.
__global__ __launch_bounds__(512, 4) void k_fused(const float* __restrict__ x,
                                                  float2* __restrict__ red1,
                                                  float2* __restrict__ red2,
                                                  float* __restrict__ lutg,
                                                  float4* __restrict__ out) {
    cg::grid_group gridg = cg::this_grid();
    __shared__ unsigned char binsL[256 * 256];   // 64 KB
    __shared__ float L[4][NBINS];                // 4 KB
    __shared__ unsigned sh[NBINS];               // 1 KB

    int t = threadIdx.x;
    int bid = blockIdx.x;
    int img = bid >> 6, tile = bid & 63;
    int ty = tile >> 3, tx = tile & 7;

    // ---- phase 0: input min/max partials (contiguous 64KB chunks) ----
    float mn = 3.4e38f, mx = -3.4e38f;
    {
        const float4* x4 = (const float4*)x;
        size_t base = (size_t)bid * 16384 + t;   // 16384 float4 per block
#pragma unroll
        for (int k = 0; k < 32; k += 4) {
            float4 v0 = x4[base + (size_t)(k + 0) * 512];
            float4 v1 = x4[base + (size_t)(k + 1) * 512];
            float4 v2 = x4[base + (size_t)(k + 2) * 512];
            float4 v3 = x4[base + (size_t)(k + 3) * 512];
            mm4(v0, mn, mx); mm4(v1, mn, mx); mm4(v2, mn, mx); mm4(v3, mn, mx);
        }
        block_minmax_all<8>(mn, mx, t);
        if (t == 0) red1[bid] = make_float2(mn, mx);
    }
    gridg.sync();

    // ---- phase 1: reduce the 512 partials (redundant per block, L2-hot) ----
    {
        float2 p = red1[t];
        mn = p.x; mx = p.y;
        block_minmax_all<8>(mn, mx, t);
    }
    float den = mx - mn;

    // ---- phase 2: bin pixels (keep in LDS) + histogram + LUT ----
    if (t < NBINS) sh[t] = 0u;
    __syncthreads();

    size_t tbase = ((size_t)img * IMH + (size_t)ty * 256) * IMW + (size_t)tx * 256;
    int lid = t & 63;
    {
        int rowoff = t >> 6;   // 0..7
        int c4 = t & 63;       // 0..63 float4 columns
        for (int it = 0; it < 32; ++it) {
            int r = (it << 3) + rowoff;
            float4 v = *(const float4*)(x + tbase + (size_t)r * IMW + (c4 << 2));
            int b[4];
            b[0] = pix_bin(v.x, mn, den);
            b[1] = pix_bin(v.y, mn, den);
            b[2] = pix_bin(v.z, mn, den);
            b[3] = pix_bin(v.w, mn, den);
#pragma unroll
            for (int j = 0; j < 4; j++) {
                bool hot = (b[j] == 255);
                unsigned long long m = __ballot(hot);
                if (!hot) atomicAdd(&sh[b[j]], 1u);
                if (lid == 0 && m) atomicAdd(&sh[255], (unsigned)__popcll(m));
            }
            uchar4 q;
            q.x = (unsigned char)b[0]; q.y = (unsigned char)b[1];
            q.z = (unsigned char)b[2]; q.w = (unsigned char)b[3];
            ((uchar4*)binsL)[(r << 6) + c4] = q;
        }
    }
    __syncthreads();

    // LUT build (threads >= 256 ride along in the shuffles with zeros)
    {
        int wid = t >> 6;
        float h = 0.0f, ex = 0.0f;
        if (t < NBINS) {
            h = (float)sh[t];
            ex = fmaxf(h - CLIP_MAXF, 0.0f);
        }
        float s = ex;
#pragma unroll
        for (int m = 1; m < 64; m <<= 1) s += __shfl_xor(s, m, 64);
        __shared__ float wpart[8];
        if (lid == 0) wpart[wid] = s;
        __syncthreads();
        float excess = wpart[0] + wpart[1] + wpart[2] + wpart[3];

        h = fminf(h, CLIP_MAXF);
        float redist   = floorf(excess * (1.0f / 256.0f));
        float residual = excess - redist * 256.0f;
        h = h + redist + (((float)t < residual) ? 1.0f : 0.0f);

        float c = h;
#pragma unroll
        for (int m = 1; m < 64; m <<= 1) {
            float o = __shfl_up(c, m, 64);
            if (lid >= m) c += o;
        }
        __shared__ float wsum[8];
        if (lid == 63) wsum[wid] = c;
        __syncthreads();
        if (t < NBINS) {
            float off = 0.0f;
            for (int i = 0; i < wid; i++) off += wsum[i];
            c += off;
            float l = fminf(floorf(c * LUT_SCALE), 255.0f);
            l = fmaxf(l, 0.0f);
            lutg[((size_t)img * NTPI + tile) * NBINS + t] = l;
        }
    }
    gridg.sync();

    // ---- phase 3: v min/max over this tile's 4 quadrants (bins from LDS) ----
    const float* lb = lutg + (size_t)img * NTPI * NBINS;
    float vmn = 3.4e38f, vmx = -3.4e38f;
    for (int q = 0; q < 4; ++q) {
        int qy = (ty << 1) + (q >> 1), qx = (tx << 1) + (q & 1);
        __syncthreads();
        load_L(lb, qy, qx, L, t);
        __syncthreads();
        int ly0 = (q >> 1) << 7, lx0 = (q & 1) << 7;
        int rowoff = t >> 5, col4 = t & 31;
        for (int it = 0; it < 8; ++it) {
            int r = (it << 4) + rowoff;              // 0..127 local row
            uchar4 qb = ((const uchar4*)binsL)[((ly0 + r) << 6) + (lx0 >> 2) + col4];
            int iy = (ty << 8) + ly0 + r;
            float tyf = ((float)iy + 0.5f) * (1.0f / 256.0f) - 0.5f;
            float wy = tyf - floorf(tyf);
            int ix0 = (tx << 8) + lx0 + (col4 << 2);
            int b[4] = {qb.x, qb.y, qb.z, qb.w};
#pragma unroll
            for (int j = 0; j < 4; j++) {
                float txf = ((float)(ix0 + j) + 0.5f) * (1.0f / 256.0f) - 0.5f;
                float wx = txf - floorf(txf);
                float v = (1.0f - wy) * ((1.0f - wx) * L[0][b[j]] + wx * L[1][b[j]]) +
                          wy * ((1.0f - wx) * L[2][b[j]] + wx * L[3][b[j]]);
                vmn = fminf(vmn, v);
                vmx = fmaxf(vmx, v);
            }
        }
    }
    block_minmax_all<8>(vmn, vmx, t);
    if (t == 0) red2[bid] = make_float2(vmn, vmx);
    gridg.sync();

    // ---- phase 4: reduce v partials, recompute, normalize, write ----
    float pmn, oscale;
    {
        float2 p = red2[t];
        float a = p.x, b2 = p.y;
        block_minmax_all<8>(a, b2, t);
        pmn = a * (1.0f / 255.0f);
        float pmx = b2 * (1.0f / 255.0f);
        oscale = 1.0f / (pmx - pmn);
    }
    for (int q = 0; q < 4; ++q) {
        int qy = (ty << 1) + (q >> 1), qx = (tx << 1) + (q & 1);
        __syncthreads();
        load_L(lb, qy, qx, L, t);
        __syncthreads();
        int ly0 = (q >> 1) << 7, lx0 = (q & 1) << 7;
        int rowoff = t >> 5, col4 = t & 31;
        for (int it = 0; it < 8; ++it) {
            int r = (it << 4) + rowoff;
            uchar4 qb = ((const uchar4*)binsL)[((ly0 + r) << 6) + (lx0 >> 2) + col4];
            int iy = (ty << 8) + ly0 + r;
            float tyf = ((float)iy + 0.5f) * (1.0f / 256.0f) - 0.5f;
            float wy = tyf - floorf(tyf);
            int ix0 = (tx << 8) + lx0 + (col4 << 2);
            int b[4] = {qb.x, qb.y, qb.z, qb.w};
            float4 o;
            float* op = &o.x;
#pragma unroll
            for (int j = 0; j < 4; j++) {
                float txf = ((float)(ix0 + j) + 0.5f) * (1.0f / 256.0f) - 0.5f;
                float wx = txf - floorf(txf);
                float v = (1.0f - wy) * ((1.0f - wx) * L[0][b[j]] + wx * L[1][b[j]]) +
                          wy * ((1.0f - wx) * L[2][b[j]] + wx * L[3][b[j]]);
                float p = v * (1.0f / 255.0f);
                op[j] = (p - pmn) * oscale;
            }
            size_t pidx = ((size_t)img * IMH + iy) * IMW + ix0;
            out[pidx >> 2] = o;
        }
    }
}

// ===================== fallback path (round-3 kernels) =====================

__global__ __launch_bounds__(256) void k_minmax_in(const float4* __restrict__ x,
                                                   float2* __restrict__ red) {
    int t = threadIdx.x;
    size_t base = (size_t)blockIdx.x * 4096 + t;
    float mn = 3.4e38f, mx = -3.4e38f;
#pragma unroll
    for (int k = 0; k < 16; k += 4) {
        float4 v0 = x[base + (size_t)(k + 0) * 256];
        float4 v1 = x[base + (size_t)(k + 1) * 256];
        float4 v2 = x[base + (size_t)(k + 2) * 256];
        float4 v3 = x[base + (size_t)(k + 3) * 256];
        mm4(v0, mn, mx); mm4(v1, mn, mx); mm4(v2, mn, mx); mm4(v3, mn, mx);
    }
    block_minmax_all<4>(mn, mx, t);
    if (t == 0) red[blockIdx.x] = make_float2(mn, mx);
}

__global__ __launch_bounds__(1024) void k_hist(const float* __restrict__ x,
                                               const float2* __restrict__ red1,
                                               float* __restrict__ lut,
                                               uchar4* __restrict__ bins) {
    int t = threadIdx.x;
    float mn, mx;
    {
        float2 p0 = red1[t];
        float2 p1 = red1[t + 1024];
        mn = fminf(p0.x, p1.x);
        mx = fmaxf(p0.y, p1.y);
        block_minmax_all<16>(mn, mx, t);
    }
    float den = mx - mn;

    __shared__ unsigned sh[NBINS];
    if (t < NBINS) sh[t] = 0u;
    __syncthreads();

    int tile = blockIdx.x;
    int img  = blockIdx.y;
    int ty = tile >> 3, tx = tile & 7;
    size_t base = ((size_t)img * IMH + (size_t)ty * 256) * IMW + (size_t)tx * 256;
    const float* xt = x + base;
    int lid = t & 63;
    int rowoff = t >> 6;
    int c4 = t & 63;

    for (int it = 0; it < 16; ++it) {
        int r = (it << 4) + rowoff;
        float4 v = *(const float4*)(xt + (size_t)r * IMW + (c4 << 2));
        int b[4];
        b[0] = pix_bin(v.x, mn, den);
        b[1] = pix_bin(v.y, mn, den);
        b[2] = pix_bin(v.z, mn, den);
        b[3] = pix_bin(v.w, mn, den);
#pragma unroll
        for (int j = 0; j < 4; j++) {
            bool hot = (b[j] == 255);
            unsigned long long m = __ballot(hot);
            if (!hot) atomicAdd(&sh[b[j]], 1u);
            if (lid == 0 && m) atomicAdd(&sh[255], (unsigned)__popcll(m));
        }
        uchar4 q;
        q.x = (unsigned char)b[0]; q.y = (unsigned char)b[1];
        q.z = (unsigned char)b[2]; q.w = (unsigned char)b[3];
        bins[(base + (size_t)r * IMW + (size_t)(c4 << 2)) >> 2] = q;
    }
    __syncthreads();

    int wid = t >> 6;
    float h = 0.0f, ex = 0.0f;
    if (t < NBINS) {
        h = (float)sh[t];
        ex = fmaxf(h - CLIP_MAXF, 0.0f);
    }
    float s = ex;
#pragma unroll
    for (int m = 1; m < 64; m <<= 1) s += __shfl_xor(s, m, 64);
    __shared__ float wpart[16];
    if (lid == 0) wpart[wid] = s;
    __syncthreads();
    float excess = wpart[0] + wpart[1] + wpart[2] + wpart[3];

    h = fminf(h, CLIP_MAXF);
    float redist   = floorf(excess * (1.0f / 256.0f));
    float residual = excess - redist * 256.0f;
    h = h + redist + (((float)t < residual) ? 1.0f : 0.0f);

    float c = h;
#pragma unroll
    for (int m = 1; m < 64; m <<= 1) {
        float o = __shfl_up(c, m, 64);
        if (lid >= m) c += o;
    }
    __shared__ float wsum[16];
    if (lid == 63) wsum[wid] = c;
    __syncthreads();
    if (t < NBINS) {
        float off = 0.0f;
        for (int i = 0; i < wid; i++) off += wsum[i];
        c += off;
        float l = fminf(floorf(c * LUT_SCALE), 255.0f);
        l = fmaxf(l, 0.0f);
        lut[((size_t)img * NTPI + tile) * NBINS + t] = l;
    }
}

template <bool FINAL>
__global__ __launch_bounds__(256) void k_apply(const uchar4* __restrict__ bins,
                                               const float* __restrict__ lut,
                                               float2* __restrict__ red2,
                                               float4* __restrict__ out) {
    __shared__ float L[4][NBINS];
    int t = threadIdx.x;

    float pmn = 0.f, oscale = 1.f;
    if (FINAL) {
        float vmn = 3.4e38f, vmx = -3.4e38f;
#pragma unroll
        for (int k = 0; k < 8; k++) {
            float2 p = red2[t + k * 256];
            vmn = fminf(vmn, p.x);
            vmx = fmaxf(vmx, p.y);
        }
        block_minmax_all<4>(vmn, vmx, t);
        pmn = vmn * (1.0f / 255.0f);
        float pmx = vmx * (1.0f / 255.0f);
        oscale = 1.0f / (pmx - pmn);
    }

    int qx = blockIdx.x, qy = blockIdx.y, img = blockIdx.z;
    const float* lb = lut + (size_t)img * NTPI * NBINS;
    load_L(lb, qy, qx, L, t | ((t >> 8) << 8));  // t<256: loads via j-loop cover 0..3
    // load_L expects 512 threads; with 256 threads which = (t>>8)+2j = {0,2} only.
    // Patch: load remaining rows explicitly.
    {
        int ci = t & 255;
        int ty2 = qy >> 1, tx2 = qx >> 1;
        int yA = (qy & 1) ? ty2 : max(ty2 - 1, 0);
        int yB = (qy & 1) ? min(ty2 + 1, GH - 1) : ty2;
        int xA = (qx & 1) ? tx2 : max(tx2 - 1, 0);
        int xB = (qx & 1) ? min(tx2 + 1, GW - 1) : tx2;
        L[0][ci] = lb[(size_t)(yA * GW + xA) * NBINS + ci];
        L[1][ci] = lb[(size_t)(yA * GW + xB) * NBINS + ci];
        L[2][ci] = lb[(size_t)(yB * GW + xA) * NBINS + ci];
        L[3][ci] = lb[(size_t)(yB * GW + xB) * NBINS + ci];
    }
    __syncthreads();

    float vmnl = 3.4e38f, vmxl = -3.4e38f;
    int gy0 = qy << 7, gx0 = qx << 7;
    int rowoff = t >> 5;
    int c4 = t & 31;

    for (int it = 0; it < 16; ++it) {
        int r = (it << 3) + rowoff;
        int iy = gy0 + r;
        int ix0 = gx0 + (c4 << 2);
        size_t pidx = ((size_t)img * IMH + iy) * IMW + ix0;
        uchar4 q = bins[pidx >> 2];
        int b[4] = {q.x, q.y, q.z, q.w};

        float tyf = ((float)iy + 0.5f) * (1.0f / 256.0f) - 0.5f;
        float wy = tyf - floorf(tyf);
        float4 o;
        float* op = &o.x;
#pragma unroll
        for (int j = 0; j < 4; j++) {
            float txf = ((float)(ix0 + j) + 0.5f) * (1.0f / 256.0f) - 0.5f;
            float wx = txf - floorf(txf);
            float v = (1.0f - wy) * ((1.0f - wx) * L[0][b[j]] + wx * L[1][b[j]]) +
                      wy * ((1.0f - wx) * L[2][b[j]] + wx * L[3][b[j]]);
            if (FINAL) {
                float p = v * (1.0f / 255.0f);
                op[j] = (p - pmn) * oscale;
            } else {
                vmnl = fminf(vmnl, v);
                vmxl = fmaxf(vmxl, v);
            }
        }
        if (FINAL) out[pidx >> 2] = o;
    }

    if (!FINAL) {
        block_minmax_all<4>(vmnl, vmxl, t);
        if (t == 0) {
            int bid = (img * 16 + qy) * 16 + qx;
            red2[bid] = make_float2(vmnl, vmxl);
        }
    }
}

extern "C" void kernel_launch(void* const* d_in, const int* in_sizes, int n_in,
                              void* d_out, int out_size, void* d_ws, size_t ws_size,
                              hipStream_t stream) {
    const float* x = (const float*)d_in[0];
    float4* out = (float4*)d_out;

    unsigned char* ws = (unsigned char*)d_ws;
    float* lut    = (float*)(ws + 64);                       // 512 KB
    float2* red1  = (float2*)(ws + 64 + 512 * 1024);         // 16 KB (2048 float2)
    float2* red2  = (float2*)(ws + 64 + 512 * 1024 + 16384); // 16 KB (2048 float2)
    uchar4* bins  = (uchar4*)(ws + 1024 * 1024);             // 33.5 MB (fallback only)

    // ---- try the fused cooperative kernel ----
    {
        void* args[] = {(void*)&x, (void*)&red1, (void*)&red2, (void*)&lut, (void*)&out};
        hipError_t e = hipLaunchCooperativeKernel((const void*)k_fused,
                                                  dim3(FUSED_BLOCKS), dim3(512),
                                                  args, 0, stream);
        if (e == hipSuccess) return;
        (void)hipGetLastError();  // clear, fall through to classic path
    }

    // ---- fallback: round-3 four-kernel path ----
    k_minmax_in<<<dim3(MM_BLOCKS), dim3(256), 0, stream>>>((const float4*)x, red1);
    k_hist<<<dim3(NTPI, NIMG), dim3(1024), 0, stream>>>(x, red1, lut, bins);
    dim3 qgrid(16, 16, NIMG);
    k_apply<false><<<qgrid, dim3(256), 0, stream>>>(bins, lut, red2, out);
    k_apply<true><<<qgrid, dim3(256), 0, stream>>>(bins, lut, red2, out);
}

// Round 5
// 113.501 us; speedup vs baseline: 2.4395x; 2.4395x over previous
//
#include <hip/hip_runtime.h>

#define NIMG 8
#define IMH 2048
#define IMW 2048
#define GH 8
#define GW 8
#define NBINS 256
#define NTPI 64                        // tiles per image
#define CLIP_MAXF 256.0f               // clip_limit*pixels//NBINS = 65536//256
#define LUT_SCALE 0.0038909912109375f  // 255/65536, exact in f32
#define LOG_GAIN_F 2.5f

#define MM_BLOCKS 2048                 // k_minmax_in grid (64 KB per block)
#define APPLY_BLOCKS (16 * 16 * NIMG)  // 2048 quadrant blocks

typedef float f32x4 __attribute__((ext_vector_type(4)));

__device__ __forceinline__ int pix_bin(float v, float mn, float den) {
    float xn = (v - mn) / den;
    float t  = LOG_GAIN_F * log2f(1.0f + xn);
    float xc = fminf(fmaxf(t, 0.0f), 1.0f);
    int b = (int)(xc * 256.0f);
    return min(max(b, 0), 255);
}

__device__ __forceinline__ void mm4(float4 v, float& mn, float& mx) {
    mn = fminf(mn, fminf(fminf(v.x, v.y), fminf(v.z, v.w)));
    mx = fmaxf(mx, fmaxf(fmaxf(v.x, v.y), fmaxf(v.z, v.w)));
}

// block min/max; result broadcast to ALL threads
template <int NWAVES>
__device__ __forceinline__ void block_minmax_all(float& mn, float& mx, int t) {
#pragma unroll
    for (int m = 32; m >= 1; m >>= 1) {
        mn = fminf(mn, __shfl_xor(mn, m, 64));
        mx = fmaxf(mx, __shfl_xor(mx, m, 64));
    }
    __shared__ float smn[NWAVES], smx[NWAVES];
    int wid = t >> 6, lid = t & 63;
    if (lid == 0) { smn[wid] = mn; smx[wid] = mx; }
    __syncthreads();
    mn = smn[0]; mx = smx[0];
#pragma unroll
    for (int i = 1; i < NWAVES; i++) { mn = fminf(mn, smn[i]); mx = fmaxf(mx, smx[i]); }
}

// ---- K1: per-block min/max of input; 4 independent chains for MLP ----
__global__ __launch_bounds__(256) void k_minmax_in(const float4* __restrict__ x,
                                                   float2* __restrict__ red) {
    int t = threadIdx.x;
    size_t base = (size_t)blockIdx.x * 4096 + t;   // 4096 float4 per block
    float mn0 = 3.4e38f, mx0 = -3.4e38f;
    float mn1 = 3.4e38f, mx1 = -3.4e38f;
    float mn2 = 3.4e38f, mx2 = -3.4e38f;
    float mn3 = 3.4e38f, mx3 = -3.4e38f;
#pragma unroll
    for (int k = 0; k < 16; k += 4) {
        float4 v0 = x[base + (size_t)(k + 0) * 256];
        float4 v1 = x[base + (size_t)(k + 1) * 256];
        float4 v2 = x[base + (size_t)(k + 2) * 256];
        float4 v3 = x[base + (size_t)(k + 3) * 256];
        mm4(v0, mn0, mx0); mm4(v1, mn1, mx1); mm4(v2, mn2, mx2); mm4(v3, mn3, mx3);
    }
    float mn = fminf(fminf(mn0, mn1), fminf(mn2, mn3));
    float mx = fmaxf(fmaxf(mx0, mx1), fmaxf(mx2, mx3));
    block_minmax_all<4>(mn, mx, t);
    if (t == 0) red[blockIdx.x] = make_float2(mn, mx);
}

// ---- K2: inline min/max reduce + per-pixel bin + per-tile hist + clip/scan -> LUT ----
// One 1024-thread block per 256x256 tile. Hot bin 255 (~68% of pixels due to
// log saturation) counted via ballot, not LDS atomic.
__global__ __launch_bounds__(1024) void k_hist(const float* __restrict__ x,
                                               const float2* __restrict__ red1,
                                               float* __restrict__ lut,
                                               uchar4* __restrict__ bins) {
    int t = threadIdx.x;

    // redundant per-block reduction of K1 partials (deterministic, L2-hot)
    float mn, mx;
    {
        float2 p0 = red1[t];
        float2 p1 = red1[t + 1024];
        mn = fminf(p0.x, p1.x);
        mx = fmaxf(p0.y, p1.y);
        block_minmax_all<16>(mn, mx, t);
    }
    float den = mx - mn;

    __shared__ unsigned sh[NBINS];
    if (t < NBINS) sh[t] = 0u;
    __syncthreads();

    int tile = blockIdx.x;  // 0..63
    int img  = blockIdx.y;  // 0..7
    int ty = tile >> 3, tx = tile & 7;

    size_t base = ((size_t)img * IMH + (size_t)ty * 256) * IMW + (size_t)tx * 256;
    const float* xt = x + base;
    int lid = t & 63;
    int rowoff = t >> 6;   // 0..15
    int c4 = t & 63;       // 0..63 float4 columns

    for (int it = 0; it < 16; ++it) {
        int r = (it << 4) + rowoff;
        float4 v = *(const float4*)(xt + (size_t)r * IMW + (c4 << 2));
        int b[4];
        b[0] = pix_bin(v.x, mn, den);
        b[1] = pix_bin(v.y, mn, den);
        b[2] = pix_bin(v.z, mn, den);
        b[3] = pix_bin(v.w, mn, den);
#pragma unroll
        for (int j = 0; j < 4; j++) {
            bool hot = (b[j] == 255);
            unsigned long long m = __ballot(hot);
            if (!hot) atomicAdd(&sh[b[j]], 1u);
            if (lid == 0 && m) atomicAdd(&sh[255], (unsigned)__popcll(m));
        }
        uchar4 q;
        q.x = (unsigned char)b[0]; q.y = (unsigned char)b[1];
        q.z = (unsigned char)b[2]; q.w = (unsigned char)b[3];
        bins[(base + (size_t)r * IMW + (size_t)(c4 << 2)) >> 2] = q;
    }
    __syncthreads();

    // ---- LUT build from LDS hist (threads >=256 ride along) ----
    int wid = t >> 6;
    float h = 0.0f, ex = 0.0f;
    if (t < NBINS) {
        h = (float)sh[t];
        ex = fmaxf(h - CLIP_MAXF, 0.0f);
    }
    float s = ex;
#pragma unroll
    for (int m = 1; m < 64; m <<= 1) s += __shfl_xor(s, m, 64);
    __shared__ float wpart[16];
    if (lid == 0) wpart[wid] = s;
    __syncthreads();
    float excess = wpart[0] + wpart[1] + wpart[2] + wpart[3];

    h = fminf(h, CLIP_MAXF);
    float redist   = floorf(excess * (1.0f / 256.0f));
    float residual = excess - redist * 256.0f;
    h = h + redist + (((float)t < residual) ? 1.0f : 0.0f);

    float c = h;
#pragma unroll
    for (int m = 1; m < 64; m <<= 1) {
        float o = __shfl_up(c, m, 64);
        if (lid >= m) c += o;
    }
    __shared__ float wsum[16];
    if (lid == 63) wsum[wid] = c;
    __syncthreads();
    if (t < NBINS) {
        float off = 0.0f;
        for (int i = 0; i < wid; i++) off += wsum[i];
        c += off;
        float l = fminf(floorf(c * LUT_SCALE), 255.0f);
        l = fmaxf(l, 0.0f);
        lut[((size_t)img * NTPI + tile) * NBINS + t] = l;
    }
}

// ---- K3/K4: per-quadrant (128x128) bilinear LUT application ----
// 4 neighbor LUTs fused into ONE float4 table -> one ds_read_b128 per pixel
// (hot-bin lanes broadcast). FINAL=false: per-block v min/max partials to red2.
// FINAL=true : inline-reduce red2, write normalized output (nontemporal).
template <bool FINAL>
__global__ __launch_bounds__(256) void k_apply(const uchar4* __restrict__ bins,
                                               const float* __restrict__ lut,
                                               float2* __restrict__ red2,
                                               float4* __restrict__ out) {
    __shared__ float4 Lq[NBINS];   // (g00, g01, g10, g11)
    int t = threadIdx.x;

    float pmn = 0.f, oscale = 1.f;
    if (FINAL) {
        float vmn = 3.4e38f, vmx = -3.4e38f;
#pragma unroll
        for (int k = 0; k < 8; k++) {
            float2 p = red2[t + k * 256];
            vmn = fminf(vmn, p.x);
            vmx = fmaxf(vmx, p.y);
        }
        block_minmax_all<4>(vmn, vmx, t);
        pmn = vmn * (1.0f / 255.0f);
        float pmx = vmx * (1.0f / 255.0f);
        oscale = 1.0f / (pmx - pmn);
    }

    int qx = blockIdx.x, qy = blockIdx.y, img = blockIdx.z;
    const float* lb = lut + (size_t)img * NTPI * NBINS;
    {
        int ty2 = qy >> 1, tx2 = qx >> 1;
        int yA = (qy & 1) ? ty2 : max(ty2 - 1, 0);
        int yB = (qy & 1) ? min(ty2 + 1, GH - 1) : ty2;
        int xA = (qx & 1) ? tx2 : max(tx2 - 1, 0);
        int xB = (qx & 1) ? min(tx2 + 1, GW - 1) : tx2;
        float4 g;
        g.x = lb[(size_t)(yA * GW + xA) * NBINS + t];
        g.y = lb[(size_t)(yA * GW + xB) * NBINS + t];
        g.z = lb[(size_t)(yB * GW + xA) * NBINS + t];
        g.w = lb[(size_t)(yB * GW + xB) * NBINS + t];
        Lq[t] = g;
    }
    __syncthreads();

    float vmnl = 3.4e38f, vmxl = -3.4e38f;
    int gy0 = qy << 7, gx0 = qx << 7;
    int rowoff = t >> 5;  // 0..7
    int c4 = t & 31;      // 0..31 (4-pixel groups across 128 cols)

    for (int it = 0; it < 16; ++it) {
        int r = (it << 3) + rowoff;
        int iy = gy0 + r;
        int ix0 = gx0 + (c4 << 2);
        size_t pidx = ((size_t)img * IMH + iy) * IMW + ix0;
        uchar4 q = bins[pidx >> 2];
        int b[4] = {q.x, q.y, q.z, q.w};

        float tyf = ((float)iy + 0.5f) * (1.0f / 256.0f) - 0.5f;
        float wy = tyf - floorf(tyf);
        float4 o;
        float* op = &o.x;
#pragma unroll
        for (int j = 0; j < 4; j++) {
            float txf = ((float)(ix0 + j) + 0.5f) * (1.0f / 256.0f) - 0.5f;
            float wx = txf - floorf(txf);
            float4 g = Lq[b[j]];   // one ds_read_b128; bin-255 lanes broadcast
            float v = (1.0f - wy) * ((1.0f - wx) * g.x + wx * g.y) +
                      wy * ((1.0f - wx) * g.z + wx * g.w);
            if (FINAL) {
                float p = v * (1.0f / 255.0f);
                op[j] = (p - pmn) * oscale;
            } else {
                vmnl = fminf(vmnl, v);
                vmxl = fmaxf(vmxl, v);
            }
        }
        if (FINAL) {
            // nontemporal: out is write-once; keep x/bins resident in L2/L3
            f32x4 ov = {o.x, o.y, o.z, o.w};
            __builtin_nontemporal_store(ov, (f32x4*)&out[pidx >> 2]);
        }
    }

    if (!FINAL) {
        block_minmax_all<4>(vmnl, vmxl, t);
        if (t == 0) {
            int bid = (img * 16 + qy) * 16 + qx;
            red2[bid] = make_float2(vmnl, vmxl);
        }
    }
}

extern "C" void kernel_launch(void* const* d_in, const int* in_sizes, int n_in,
                              void* d_out, int out_size, void* d_ws, size_t ws_size,
                              hipStream_t stream) {
    const float* x = (const float*)d_in[0];
    float4* out = (float4*)d_out;

    unsigned char* ws = (unsigned char*)d_ws;
    float* lut    = (float*)(ws + 64);                       // 512 KB
    float2* red1  = (float2*)(ws + 64 + 512 * 1024);         // 16 KB (2048 float2)
    float2* red2  = (float2*)(ws + 64 + 512 * 1024 + 16384); // 16 KB (2048 float2)
    uchar4* bins  = (uchar4*)(ws + 1024 * 1024);             // 33.5 MB

    k_minmax_in<<<dim3(MM_BLOCKS), dim3(256), 0, stream>>>((const float4*)x, red1);
    k_hist<<<dim3(NTPI, NIMG), dim3(1024), 0, stream>>>(x, red1, lut, bins);
    dim3 qgrid(16, 16, NIMG);
    k_apply<false><<<qgrid, dim3(256), 0, stream>>>(bins, lut, red2, out);
    k_apply<true><<<qgrid, dim3(256), 0, stream>>>(bins, lut, red2, out);
}

// Round 6
// 109.281 us; speedup vs baseline: 2.5337x; 1.0386x over previous
//
#include <hip/hip_runtime.h>

#define NIMG 8
#define IMH 2048
#define IMW 2048
#define GH 8
#define GW 8
#define NBINS 256
#define NTPI 64                        // tiles per image
#define CLIP_MAXF 256.0f               // clip_limit*pixels//NBINS = 65536//256
#define LUT_SCALE 0.0038909912109375f  // 255/65536, exact in f32
#define LOG_GAIN_F 2.5f

#define MM_BLOCKS 2048                 // k_minmax_in grid (64 KB per block)

typedef float f32x4 __attribute__((ext_vector_type(4)));

// fast bin: wave-uniform inv_den hoists the divide; __log2f = 1 v_log_f32
// (input in [1,2] -> ~1 ulp; worst case shifts a boundary pixel by 1 bin =
// 0.0039 output units, threshold is 0.02)
__device__ __forceinline__ int pix_bin(float v, float mn, float inv_den) {
    float xn = (v - mn) * inv_den;
    float t  = LOG_GAIN_F * __log2f(1.0f + xn);
    float xc = fminf(fmaxf(t, 0.0f), 1.0f);
    int b = (int)(xc * 256.0f);
    return min(max(b, 0), 255);
}

__device__ __forceinline__ void mm4(float4 v, float& mn, float& mx) {
    mn = fminf(mn, fminf(fminf(v.x, v.y), fminf(v.z, v.w)));
    mx = fmaxf(mx, fmaxf(fmaxf(v.x, v.y), fmaxf(v.z, v.w)));
}

// block min/max; result broadcast to ALL threads
template <int NWAVES>
__device__ __forceinline__ void block_minmax_all(float& mn, float& mx, int t) {
#pragma unroll
    for (int m = 32; m >= 1; m >>= 1) {
        mn = fminf(mn, __shfl_xor(mn, m, 64));
        mx = fmaxf(mx, __shfl_xor(mx, m, 64));
    }
    __shared__ float smn[NWAVES], smx[NWAVES];
    int wid = t >> 6, lid = t & 63;
    if (lid == 0) { smn[wid] = mn; smx[wid] = mx; }
    __syncthreads();
    mn = smn[0]; mx = smx[0];
#pragma unroll
    for (int i = 1; i < NWAVES; i++) { mn = fminf(mn, smn[i]); mx = fmaxf(mx, smx[i]); }
}

// ---- K1: per-block min/max of input; 4 independent chains for MLP ----
__global__ __launch_bounds__(256) void k_minmax_in(const float4* __restrict__ x,
                                                   float2* __restrict__ red) {
    int t = threadIdx.x;
    size_t base = (size_t)blockIdx.x * 4096 + t;   // 4096 float4 per block
    float mn0 = 3.4e38f, mx0 = -3.4e38f;
    float mn1 = 3.4e38f, mx1 = -3.4e38f;
    float mn2 = 3.4e38f, mx2 = -3.4e38f;
    float mn3 = 3.4e38f, mx3 = -3.4e38f;
#pragma unroll
    for (int k = 0; k < 16; k += 4) {
        float4 v0 = x[base + (size_t)(k + 0) * 256];
        float4 v1 = x[base + (size_t)(k + 1) * 256];
        float4 v2 = x[base + (size_t)(k + 2) * 256];
        float4 v3 = x[base + (size_t)(k + 3) * 256];
        mm4(v0, mn0, mx0); mm4(v1, mn1, mx1); mm4(v2, mn2, mx2); mm4(v3, mn3, mx3);
    }
    float mn = fminf(fminf(mn0, mn1), fminf(mn2, mn3));
    float mx = fmaxf(fmaxf(mx0, mx1), fmaxf(mx2, mx3));
    block_minmax_all<4>(mn, mx, t);
    if (t == 0) red[blockIdx.x] = make_float2(mn, mx);
}

// ---- K2: inline min/max reduce + per-pixel bin + per-tile hist + clip/scan -> LUT ----
// One 1024-thread block per 256x256 tile. Hot bin 255 (~68% of pixels due to
// log saturation) counted via ballot+register accumulation: ONE LDS atomic
// per wave for the hot bin, issued after the loop.
__global__ __launch_bounds__(1024) void k_hist(const float* __restrict__ x,
                                               const float2* __restrict__ red1,
                                               float* __restrict__ lut,
                                               uchar4* __restrict__ bins) {
    int t = threadIdx.x;

    // redundant per-block reduction of K1 partials (deterministic, L2-hot)
    float mn, mx;
    {
        float2 p0 = red1[t];
        float2 p1 = red1[t + 1024];
        mn = fminf(p0.x, p1.x);
        mx = fmaxf(p0.y, p1.y);
        block_minmax_all<16>(mn, mx, t);
    }
    float inv_den = 1.0f / (mx - mn);

    __shared__ unsigned sh[NBINS];
    if (t < NBINS) sh[t] = 0u;
    __syncthreads();

    int tile = blockIdx.x;  // 0..63
    int img  = blockIdx.y;  // 0..7
    int ty = tile >> 3, tx = tile & 7;

    size_t base = ((size_t)img * IMH + (size_t)ty * 256) * IMW + (size_t)tx * 256;
    const float* xt = x + base;
    int lid = t & 63;
    int rowoff = t >> 6;   // 0..15
    int c4 = t & 63;       // 0..63 float4 columns

    unsigned hotacc = 0;
    for (int it = 0; it < 16; ++it) {
        int r = (it << 4) + rowoff;
        float4 v = *(const float4*)(xt + (size_t)r * IMW + (c4 << 2));
        int b[4];
        b[0] = pix_bin(v.x, mn, inv_den);
        b[1] = pix_bin(v.y, mn, inv_den);
        b[2] = pix_bin(v.z, mn, inv_den);
        b[3] = pix_bin(v.w, mn, inv_den);
#pragma unroll
        for (int j = 0; j < 4; j++) {
            bool hot = (b[j] == 255);
            unsigned long long m = __ballot(hot);
            if (!hot) atomicAdd(&sh[b[j]], 1u);
            hotacc += (unsigned)__popcll(m);   // uniform across wave
        }
        uchar4 q;
        q.x = (unsigned char)b[0]; q.y = (unsigned char)b[1];
        q.z = (unsigned char)b[2]; q.w = (unsigned char)b[3];
        bins[(base + (size_t)r * IMW + (size_t)(c4 << 2)) >> 2] = q;
    }
    if (lid == 0 && hotacc) atomicAdd(&sh[255], hotacc);
    __syncthreads();

    // ---- LUT build from LDS hist (threads >=256 ride along) ----
    int wid = t >> 6;
    float h = 0.0f, ex = 0.0f;
    if (t < NBINS) {
        h = (float)sh[t];
        ex = fmaxf(h - CLIP_MAXF, 0.0f);
    }
    float s = ex;
#pragma unroll
    for (int m = 1; m < 64; m <<= 1) s += __shfl_xor(s, m, 64);
    __shared__ float wpart[16];
    if (lid == 0) wpart[wid] = s;
    __syncthreads();
    float excess = wpart[0] + wpart[1] + wpart[2] + wpart[3];

    h = fminf(h, CLIP_MAXF);
    float redist   = floorf(excess * (1.0f / 256.0f));
    float residual = excess - redist * 256.0f;
    h = h + redist + (((float)t < residual) ? 1.0f : 0.0f);

    float c = h;
#pragma unroll
    for (int m = 1; m < 64; m <<= 1) {
        float o = __shfl_up(c, m, 64);
        if (lid >= m) c += o;
    }
    __shared__ float wsum[16];
    if (lid == 63) wsum[wid] = c;
    __syncthreads();
    if (t < NBINS) {
        float off = 0.0f;
        for (int i = 0; i < wid; i++) off += wsum[i];
        c += off;
        float l = fminf(floorf(c * LUT_SCALE), 255.0f);
        l = fmaxf(l, 0.0f);
        lut[((size_t)img * NTPI + tile) * NBINS + t] = l;
    }
}

// ---- K3/K4: per-quadrant (128x128) bilinear LUT application ----
// 4 neighbor LUTs fused into ONE float4 table -> one ds_read_b128 per pixel
// (hot-bin lanes broadcast). wx weights are column-invariant -> hoisted.
// FINAL=false: per-block v min/max partials to red2.
// FINAL=true : inline-reduce red2, write normalized output (nontemporal).
template <bool FINAL>
__global__ __launch_bounds__(256) void k_apply(const uchar4* __restrict__ bins,
                                               const float* __restrict__ lut,
                                               float2* __restrict__ red2,
                                               float4* __restrict__ out) {
    __shared__ float4 Lq[NBINS];   // (g00, g01, g10, g11)
    int t = threadIdx.x;

    float pmn = 0.f, oscale = 1.f;
    if (FINAL) {
        float vmn = 3.4e38f, vmx = -3.4e38f;
#pragma unroll
        for (int k = 0; k < 8; k++) {
            float2 p = red2[t + k * 256];
            vmn = fminf(vmn, p.x);
            vmx = fmaxf(vmx, p.y);
        }
        block_minmax_all<4>(vmn, vmx, t);
        pmn = vmn * (1.0f / 255.0f);
        float pmx = vmx * (1.0f / 255.0f);
        oscale = 1.0f / (pmx - pmn);
    }

    int qx = blockIdx.x, qy = blockIdx.y, img = blockIdx.z;
    const float* lb = lut + (size_t)img * NTPI * NBINS;
    {
        int ty2 = qy >> 1, tx2 = qx >> 1;
        int yA = (qy & 1) ? ty2 : max(ty2 - 1, 0);
        int yB = (qy & 1) ? min(ty2 + 1, GH - 1) : ty2;
        int xA = (qx & 1) ? tx2 : max(tx2 - 1, 0);
        int xB = (qx & 1) ? min(tx2 + 1, GW - 1) : tx2;
        float4 g;
        g.x = lb[(size_t)(yA * GW + xA) * NBINS + t];
        g.y = lb[(size_t)(yA * GW + xB) * NBINS + t];
        g.z = lb[(size_t)(yB * GW + xA) * NBINS + t];
        g.w = lb[(size_t)(yB * GW + xB) * NBINS + t];
        Lq[t] = g;
    }
    __syncthreads();

    float vmnl = 3.4e38f, vmxl = -3.4e38f;
    int gy0 = qy << 7, gx0 = qx << 7;
    int rowoff = t >> 5;  // 0..7
    int c4 = t & 31;      // 0..31 (4-pixel groups across 128 cols)
    int ix0 = gx0 + (c4 << 2);

    // column weights are row-invariant: hoist out of the row loop
    float wxv[4];
#pragma unroll
    for (int j = 0; j < 4; j++) {
        float txf = ((float)(ix0 + j) + 0.5f) * (1.0f / 256.0f) - 0.5f;
        wxv[j] = txf - floorf(txf);
    }

    for (int it = 0; it < 16; ++it) {
        int r = (it << 3) + rowoff;
        int iy = gy0 + r;
        size_t pidx = ((size_t)img * IMH + iy) * IMW + ix0;
        uchar4 q = bins[pidx >> 2];
        int b[4] = {q.x, q.y, q.z, q.w};

        float tyf = ((float)iy + 0.5f) * (1.0f / 256.0f) - 0.5f;
        float wy = tyf - floorf(tyf);
        float4 o;
        float* op = &o.x;
#pragma unroll
        for (int j = 0; j < 4; j++) {
            float4 g = Lq[b[j]];   // one ds_read_b128; bin-255 lanes broadcast
            float a = g.x + wxv[j] * (g.y - g.x);
            float bb = g.z + wxv[j] * (g.w - g.z);
            float v = a + wy * (bb - a);
            if (FINAL) {
                float p = v * (1.0f / 255.0f);
                op[j] = (p - pmn) * oscale;
            } else {
                vmnl = fminf(vmnl, v);
                vmxl = fmaxf(vmxl, v);
            }
        }
        if (FINAL) {
            // nontemporal: out is write-once; keep x/bins resident in L2/L3
            f32x4 ov = {o.x, o.y, o.z, o.w};
            __builtin_nontemporal_store(ov, (f32x4*)&out[pidx >> 2]);
        }
    }

    if (!FINAL) {
        block_minmax_all<4>(vmnl, vmxl, t);
        if (t == 0) {
            int bid = (img * 16 + qy) * 16 + qx;
            red2[bid] = make_float2(vmnl, vmxl);
        }
    }
}

extern "C" void kernel_launch(void* const* d_in, const int* in_sizes, int n_in,
                              void* d_out, int out_size, void* d_ws, size_t ws_size,
                              hipStream_t stream) {
    const float* x = (const float*)d_in[0];
    float4* out = (float4*)d_out;

    unsigned char* ws = (unsigned char*)d_ws;
    float* lut    = (float*)(ws + 64);                       // 512 KB
    float2* red1  = (float2*)(ws + 64 + 512 * 1024);         // 16 KB (2048 float2)
    float2* red2  = (float2*)(ws + 64 + 512 * 1024 + 16384); // 16 KB (2048 float2)
    uchar4* bins  = (uchar4*)(ws + 1024 * 1024);             // 33.5 MB

    k_minmax_in<<<dim3(MM_BLOCKS), dim3(256), 0, stream>>>((const float4*)x, red1);
    k_hist<<<dim3(NTPI, NIMG), dim3(1024), 0, stream>>>(x, red1, lut, bins);
    dim3 qgrid(16, 16, NIMG);
    k_apply<false><<<qgrid, dim3(256), 0, stream>>>(bins, lut, red2, out);
    k_apply<true><<<qgrid, dim3(256), 0, stream>>>(bins, lut, red2, out);
}

// Round 7
// 106.015 us; speedup vs baseline: 2.6117x; 1.0308x over previous
//
#include <hip/hip_runtime.h>

#define NIMG 8
#define IMH 2048
#define IMW 2048
#define GH 8
#define GW 8
#define NBINS 256
#define NTPI 64                        // tiles per image
#define CLIP_MAXF 256.0f               // clip_limit*pixels//NBINS = 65536//256
#define LUT_SCALE 0.0038909912109375f  // 255/65536, exact in f32
#define LOG_GAIN_F 2.5f

#define MM_BLOCKS 2048                 // k_minmax_in grid (64 KB per block)

typedef float f32x4 __attribute__((ext_vector_type(4)));

// fast bin: wave-uniform inv_den hoists the divide; __log2f = 1 v_log_f32
// (input in [1,2] -> ~1 ulp; worst case shifts a boundary pixel by 1 bin =
// 0.0039 output units, threshold is 0.02)
__device__ __forceinline__ int pix_bin(float v, float mn, float inv_den) {
    float xn = (v - mn) * inv_den;
    float t  = LOG_GAIN_F * __log2f(1.0f + xn);
    float xc = fminf(fmaxf(t, 0.0f), 1.0f);
    int b = (int)(xc * 256.0f);
    return min(max(b, 0), 255);
}

__device__ __forceinline__ void mm4(float4 v, float& mn, float& mx) {
    mn = fminf(mn, fminf(fminf(v.x, v.y), fminf(v.z, v.w)));
    mx = fmaxf(mx, fmaxf(fmaxf(v.x, v.y), fmaxf(v.z, v.w)));
}

// block min/max; result broadcast to ALL threads
template <int NWAVES>
__device__ __forceinline__ void block_minmax_all(float& mn, float& mx, int t) {
#pragma unroll
    for (int m = 32; m >= 1; m >>= 1) {
        mn = fminf(mn, __shfl_xor(mn, m, 64));
        mx = fmaxf(mx, __shfl_xor(mx, m, 64));
    }
    __shared__ float smn[NWAVES], smx[NWAVES];
    int wid = t >> 6, lid = t & 63;
    if (lid == 0) { smn[wid] = mn; smx[wid] = mx; }
    __syncthreads();
    mn = smn[0]; mx = smx[0];
#pragma unroll
    for (int i = 1; i < NWAVES; i++) { mn = fminf(mn, smn[i]); mx = fmaxf(mx, smx[i]); }
}

// ---- K1: per-block min/max of input; 8 loads in flight per batch ----
// v[8] keeps VGPR <= 64 so 8 waves/SIMD stay resident: in-flight bytes
// = 32 waves/CU * 64 * 8 * 16B = 256KB/CU >> latency-BW product.
__global__ __launch_bounds__(256) void k_minmax_in(const float4* __restrict__ x,
                                                   float2* __restrict__ red) {
    int t = threadIdx.x;
    size_t base = (size_t)blockIdx.x * 4096 + t;   // 4096 float4 per block
    float mn = 3.4e38f, mx = -3.4e38f;
#pragma unroll
    for (int half = 0; half < 2; ++half) {
        float4 v[8];
#pragma unroll
        for (int k = 0; k < 8; ++k)
            v[k] = x[base + (size_t)(half * 8 + k) * 256];
#pragma unroll
        for (int k = 0; k < 8; ++k) mm4(v[k], mn, mx);
    }
    block_minmax_all<4>(mn, mx, t);
    if (t == 0) red[blockIdx.x] = make_float2(mn, mx);
}

// ---- K2: inline min/max reduce + per-pixel bin + per-tile hist + clip/scan -> LUT ----
// One 1024-thread block per 256x256 tile. Hot bin 255 (~68% of pixels due to
// log saturation) counted in a per-thread REGISTER; one wave-reduce + one LDS
// atomic per wave at the end. Non-hot bins: predicated LDS atomic.
__global__ __launch_bounds__(1024) void k_hist(const float* __restrict__ x,
                                               const float2* __restrict__ red1,
                                               float* __restrict__ lut,
                                               uchar4* __restrict__ bins) {
    int t = threadIdx.x;

    // redundant per-block reduction of K1 partials (deterministic, L2-hot)
    float mn, mx;
    {
        float2 p0 = red1[t];
        float2 p1 = red1[t + 1024];
        mn = fminf(p0.x, p1.x);
        mx = fmaxf(p0.y, p1.y);
        block_minmax_all<16>(mn, mx, t);
    }
    float inv_den = 1.0f / (mx - mn);

    __shared__ unsigned sh[NBINS];
    if (t < NBINS) sh[t] = 0u;
    __syncthreads();

    int tile = blockIdx.x;  // 0..63
    int img  = blockIdx.y;  // 0..7
    int ty = tile >> 3, tx = tile & 7;

    size_t base = ((size_t)img * IMH + (size_t)ty * 256) * IMW + (size_t)tx * 256;
    const float* xt = x + base;
    int lid = t & 63;
    int rowoff = t >> 6;   // 0..15
    int c4 = t & 63;       // 0..63 float4 columns

    int hotcnt = 0;
    for (int it = 0; it < 16; it += 2) {
        int r0 = (it << 4) + rowoff;
        int r1 = ((it + 1) << 4) + rowoff;
        float4 va = *(const float4*)(xt + (size_t)r0 * IMW + (c4 << 2));
        float4 vb = *(const float4*)(xt + (size_t)r1 * IMW + (c4 << 2));

        int ba[4], bb[4];
        ba[0] = pix_bin(va.x, mn, inv_den); ba[1] = pix_bin(va.y, mn, inv_den);
        ba[2] = pix_bin(va.z, mn, inv_den); ba[3] = pix_bin(va.w, mn, inv_den);
        bb[0] = pix_bin(vb.x, mn, inv_den); bb[1] = pix_bin(vb.y, mn, inv_den);
        bb[2] = pix_bin(vb.z, mn, inv_den); bb[3] = pix_bin(vb.w, mn, inv_den);

#pragma unroll
        for (int j = 0; j < 4; j++) {
            hotcnt += (ba[j] == 255);
            if (ba[j] != 255) atomicAdd(&sh[ba[j]], 1u);
            hotcnt += (bb[j] == 255);
            if (bb[j] != 255) atomicAdd(&sh[bb[j]], 1u);
        }
        uchar4 qa, qb;
        qa.x = (unsigned char)ba[0]; qa.y = (unsigned char)ba[1];
        qa.z = (unsigned char)ba[2]; qa.w = (unsigned char)ba[3];
        qb.x = (unsigned char)bb[0]; qb.y = (unsigned char)bb[1];
        qb.z = (unsigned char)bb[2]; qb.w = (unsigned char)bb[3];
        bins[(base + (size_t)r0 * IMW + (size_t)(c4 << 2)) >> 2] = qa;
        bins[(base + (size_t)r1 * IMW + (size_t)(c4 << 2)) >> 2] = qb;
    }
    // one atomic per wave for the hot bin
#pragma unroll
    for (int m = 1; m < 64; m <<= 1) hotcnt += __shfl_xor(hotcnt, m, 64);
    if (lid == 0 && hotcnt) atomicAdd(&sh[255], (unsigned)hotcnt);
    __syncthreads();

    // ---- LUT build from LDS hist (threads >=256 ride along) ----
    int wid = t >> 6;
    float h = 0.0f, ex = 0.0f;
    if (t < NBINS) {
        h = (float)sh[t];
        ex = fmaxf(h - CLIP_MAXF, 0.0f);
    }
    float s = ex;
#pragma unroll
    for (int m = 1; m < 64; m <<= 1) s += __shfl_xor(s, m, 64);
    __shared__ float wpart[16];
    if (lid == 0) wpart[wid] = s;
    __syncthreads();
    float excess = wpart[0] + wpart[1] + wpart[2] + wpart[3];

    h = fminf(h, CLIP_MAXF);
    float redist   = floorf(excess * (1.0f / 256.0f));
    float residual = excess - redist * 256.0f;
    h = h + redist + (((float)t < residual) ? 1.0f : 0.0f);

    float c = h;
#pragma unroll
    for (int m = 1; m < 64; m <<= 1) {
        float o = __shfl_up(c, m, 64);
        if (lid >= m) c += o;
    }
    __shared__ float wsum[16];
    if (lid == 63) wsum[wid] = c;
    __syncthreads();
    if (t < NBINS) {
        float off = 0.0f;
        for (int i = 0; i < wid; i++) off += wsum[i];
        c += off;
        float l = fminf(floorf(c * LUT_SCALE), 255.0f);
        l = fmaxf(l, 0.0f);
        lut[((size_t)img * NTPI + tile) * NBINS + t] = l;
    }
}

// ---- K3/K4: per-quadrant (128x128) bilinear LUT application ----
// 4 neighbor LUTs fused into ONE float4 table -> one ds_read_b128 per pixel.
// FINAL=true folds the output normalize (v/255 - pmn)*oscale INTO Lq, so the
// bilinear result IS the final value. 2 rows unrolled per iter (2 loads deep).
template <bool FINAL>
__global__ __launch_bounds__(256) void k_apply(const uchar4* __restrict__ bins,
                                               const float* __restrict__ lut,
                                               float2* __restrict__ red2,
                                               float4* __restrict__ out) {
    __shared__ float4 Lq[NBINS];   // (g00, g01, g10, g11), possibly pre-normalized
    int t = threadIdx.x;

    float s1 = 1.0f, s2 = 0.0f;    // Lq' = Lq*s1 + s2
    if (FINAL) {
        float vmn = 3.4e38f, vmx = -3.4e38f;
#pragma unroll
        for (int k = 0; k < 8; k++) {
            float2 p = red2[t + k * 256];
            vmn = fminf(vmn, p.x);
            vmx = fmaxf(vmx, p.y);
        }
        block_minmax_all<4>(vmn, vmx, t);
        float pmn = vmn * (1.0f / 255.0f);
        float pmx = vmx * (1.0f / 255.0f);
        float oscale = 1.0f / (pmx - pmn);
        s1 = oscale * (1.0f / 255.0f);
        s2 = -pmn * oscale;
    }

    int qx = blockIdx.x, qy = blockIdx.y, img = blockIdx.z;
    const float* lb = lut + (size_t)img * NTPI * NBINS;
    {
        int ty2 = qy >> 1, tx2 = qx >> 1;
        int yA = (qy & 1) ? ty2 : max(ty2 - 1, 0);
        int yB = (qy & 1) ? min(ty2 + 1, GH - 1) : ty2;
        int xA = (qx & 1) ? tx2 : max(tx2 - 1, 0);
        int xB = (qx & 1) ? min(tx2 + 1, GW - 1) : tx2;
        float4 g;
        g.x = lb[(size_t)(yA * GW + xA) * NBINS + t] * s1 + s2;
        g.y = lb[(size_t)(yA * GW + xB) * NBINS + t] * s1 + s2;
        g.z = lb[(size_t)(yB * GW + xA) * NBINS + t] * s1 + s2;
        g.w = lb[(size_t)(yB * GW + xB) * NBINS + t] * s1 + s2;
        Lq[t] = g;
    }
    __syncthreads();

    float vmnl = 3.4e38f, vmxl = -3.4e38f;
    int gy0 = qy << 7, gx0 = qx << 7;
    int rowoff = t >> 5;  // 0..7
    int c4 = t & 31;      // 0..31 (4-pixel groups across 128 cols)
    int ix0 = gx0 + (c4 << 2);

    // column weights are row-invariant: hoist out of the row loop
    float wxv[4];
#pragma unroll
    for (int j = 0; j < 4; j++) {
        float txf = ((float)(ix0 + j) + 0.5f) * (1.0f / 256.0f) - 0.5f;
        wxv[j] = txf - floorf(txf);
    }

    for (int it = 0; it < 16; it += 2) {
        int r0 = (it << 3) + rowoff;
        int r1 = ((it + 1) << 3) + rowoff;
        int iy0 = gy0 + r0, iy1 = gy0 + r1;
        size_t p0 = ((size_t)img * IMH + iy0) * IMW + ix0;
        size_t p1 = ((size_t)img * IMH + iy1) * IMW + ix0;
        uchar4 qa = bins[p0 >> 2];
        uchar4 qb = bins[p1 >> 2];

#pragma unroll
        for (int half = 0; half < 2; ++half) {
            uchar4 q = half ? qb : qa;
            int iy = half ? iy1 : iy0;
            size_t pidx = half ? p1 : p0;
            int b[4] = {q.x, q.y, q.z, q.w};
            float tyf = ((float)iy + 0.5f) * (1.0f / 256.0f) - 0.5f;
            float wy = tyf - floorf(tyf);
            float4 o;
            float* op = &o.x;
#pragma unroll
            for (int j = 0; j < 4; j++) {
                float4 g = Lq[b[j]];   // one ds_read_b128; bin-255 lanes broadcast
                float a = g.x + wxv[j] * (g.y - g.x);
                float bbv = g.z + wxv[j] * (g.w - g.z);
                float v = a + wy * (bbv - a);
                if (FINAL) {
                    op[j] = v;          // normalize already folded into Lq
                } else {
                    vmnl = fminf(vmnl, v);
                    vmxl = fmaxf(vmxl, v);
                }
            }
            if (FINAL) {
                f32x4 ov = {o.x, o.y, o.z, o.w};
                __builtin_nontemporal_store(ov, (f32x4*)&out[pidx >> 2]);
            }
        }
    }

    if (!FINAL) {
        block_minmax_all<4>(vmnl, vmxl, t);
        if (t == 0) {
            int bid = (img * 16 + qy) * 16 + qx;
            red2[bid] = make_float2(vmnl, vmxl);
        }
    }
}

extern "C" void kernel_launch(void* const* d_in, const int* in_sizes, int n_in,
                              void* d_out, int out_size, void* d_ws, size_t ws_size,
                              hipStream_t stream) {
    const float* x = (const float*)d_in[0];
    float4* out = (float4*)d_out;

    unsigned char* ws = (unsigned char*)d_ws;
    float* lut    = (float*)(ws + 64);                       // 512 KB
    float2* red1  = (float2*)(ws + 64 + 512 * 1024);         // 16 KB (2048 float2)
    float2* red2  = (float2*)(ws + 64 + 512 * 1024 + 16384); // 16 KB (2048 float2)
    uchar4* bins  = (uchar4*)(ws + 1024 * 1024);             // 33.5 MB

    k_minmax_in<<<dim3(MM_BLOCKS), dim3(256), 0, stream>>>((const float4*)x, red1);
    k_hist<<<dim3(NTPI, NIMG), dim3(1024), 0, stream>>>(x, red1, lut, bins);
    dim3 qgrid(16, 16, NIMG);
    k_apply<false><<<qgrid, dim3(256), 0, stream>>>(bins, lut, red2, out);
    k_apply<true><<<qgrid, dim3(256), 0, stream>>>(bins, lut, red2, out);
}

// Round 8
// 105.020 us; speedup vs baseline: 2.6365x; 1.0095x over previous
//
#include <hip/hip_runtime.h>

#define NIMG 8
#define IMH 2048
#define IMW 2048
#define GH 8
#define GW 8
#define NBINS 256
#define NTPI 64                        // tiles per image
#define CLIP_MAXF 256.0f               // clip_limit*pixels//NBINS = 65536//256
#define LUT_SCALE 0.0038909912109375f  // 255/65536, exact in f32
#define LOG_GAIN_F 2.5f

#define MM_BLOCKS 2048                 // k_minmax_in grid (64 KB per block)

typedef float f32x4 __attribute__((ext_vector_type(4)));

// fast bin: wave-uniform inv_den hoists the divide; __log2f = 1 v_log_f32
__device__ __forceinline__ int pix_bin(float v, float mn, float inv_den) {
    float xn = (v - mn) * inv_den;
    float t  = LOG_GAIN_F * __log2f(1.0f + xn);
    float xc = fminf(fmaxf(t, 0.0f), 1.0f);
    int b = (int)(xc * 256.0f);
    return min(max(b, 0), 255);
}

__device__ __forceinline__ void mm4(float4 v, float& mn, float& mx) {
    mn = fminf(mn, fminf(fminf(v.x, v.y), fminf(v.z, v.w)));
    mx = fmaxf(mx, fmaxf(fmaxf(v.x, v.y), fmaxf(v.z, v.w)));
}

template <int NWAVES>
__device__ __forceinline__ void block_minmax_all(float& mn, float& mx, int t) {
#pragma unroll
    for (int m = 32; m >= 1; m >>= 1) {
        mn = fminf(mn, __shfl_xor(mn, m, 64));
        mx = fmaxf(mx, __shfl_xor(mx, m, 64));
    }
    __shared__ float smn[NWAVES], smx[NWAVES];
    int wid = t >> 6, lid = t & 63;
    if (lid == 0) { smn[wid] = mn; smx[wid] = mx; }
    __syncthreads();
    mn = smn[0]; mx = smx[0];
#pragma unroll
    for (int i = 1; i < NWAVES; i++) { mn = fminf(mn, smn[i]); mx = fmaxf(mx, smx[i]); }
}

template <int NWAVES>
__device__ __forceinline__ void block_min_all(float& mn, int t) {
#pragma unroll
    for (int m = 32; m >= 1; m >>= 1) mn = fminf(mn, __shfl_xor(mn, m, 64));
    __shared__ float smn[NWAVES];
    int wid = t >> 6, lid = t & 63;
    if (lid == 0) smn[wid] = mn;
    __syncthreads();
    mn = smn[0];
#pragma unroll
    for (int i = 1; i < NWAVES; i++) mn = fminf(mn, smn[i]);
}

// ---- K1: per-block min/max of input; 8 loads in flight, 8 blocks/CU ----
__global__ __launch_bounds__(256, 8) void k_minmax_in(const float4* __restrict__ x,
                                                      float2* __restrict__ red) {
    int t = threadIdx.x;
    size_t base = (size_t)blockIdx.x * 4096 + t;   // 4096 float4 per block
    float mn = 3.4e38f, mx = -3.4e38f;
#pragma unroll
    for (int half = 0; half < 2; ++half) {
        float4 v[8];
#pragma unroll
        for (int k = 0; k < 8; ++k)
            v[k] = x[base + (size_t)(half * 8 + k) * 256];
#pragma unroll
        for (int k = 0; k < 8; ++k) mm4(v[k], mn, mx);
    }
    block_minmax_all<4>(mn, mx, t);
    if (t == 0) red[blockIdx.x] = make_float2(mn, mx);
}

// ---- K2: min/max reduce + bin + per-tile hist + clip/scan -> LUT ----
// 512 threads per 256x256 tile (2 blocks/CU guaranteed). bins written in
// QUADRANT-MAJOR layout: quadrant gq = img*256 + qy*16 + qx holds a dense
// 128x128 byte block (uchar4 offset = (r&127)*32 + (c4&31)).
__global__ __launch_bounds__(512, 4) void k_hist(const float* __restrict__ x,
                                                 const float2* __restrict__ red1,
                                                 float* __restrict__ lut,
                                                 uchar4* __restrict__ binsq) {
    int t = threadIdx.x;

    float mn, mx;
    {
        float2 p0 = red1[t];
        float2 p1 = red1[t + 512];
        float2 p2 = red1[t + 1024];
        float2 p3 = red1[t + 1536];
        mn = fminf(fminf(p0.x, p1.x), fminf(p2.x, p3.x));
        mx = fmaxf(fmaxf(p0.y, p1.y), fmaxf(p2.y, p3.y));
        block_minmax_all<8>(mn, mx, t);
    }
    float inv_den = 1.0f / (mx - mn);

    __shared__ unsigned sh[NBINS];
    if (t < NBINS) sh[t] = 0u;
    __syncthreads();

    int tile = blockIdx.x;  // 0..63
    int img  = blockIdx.y;  // 0..7
    int ty = tile >> 3, tx = tile & 7;

    size_t base = ((size_t)img * IMH + (size_t)ty * 256) * IMW + (size_t)tx * 256;
    const float* xt = x + base;
    int lid = t & 63;
    int rowoff = t >> 6;   // 0..7
    int c4 = t & 63;       // 0..63 float4 columns
    // quadrant-major write precompute: qc = c4>=32
    int qc = c4 >> 5;
    int gq_base = img * 256 + (2 * ty) * 16 + (2 * tx) + qc;  // + 16*qr
    int qoff_c = c4 & 31;

    int hotcnt = 0;
    for (int it = 0; it < 16; ++it) {
        int r0 = (it << 4) + rowoff;
        int r1 = (it << 4) + 8 + rowoff;
        float4 va = *(const float4*)(xt + (size_t)r0 * IMW + (c4 << 2));
        float4 vb = *(const float4*)(xt + (size_t)r1 * IMW + (c4 << 2));

        int ba[4], bb[4];
        ba[0] = pix_bin(va.x, mn, inv_den); ba[1] = pix_bin(va.y, mn, inv_den);
        ba[2] = pix_bin(va.z, mn, inv_den); ba[3] = pix_bin(va.w, mn, inv_den);
        bb[0] = pix_bin(vb.x, mn, inv_den); bb[1] = pix_bin(vb.y, mn, inv_den);
        bb[2] = pix_bin(vb.z, mn, inv_den); bb[3] = pix_bin(vb.w, mn, inv_den);

#pragma unroll
        for (int j = 0; j < 4; j++) {
            hotcnt += (ba[j] == 255);
            if (ba[j] != 255) atomicAdd(&sh[ba[j]], 1u);
            hotcnt += (bb[j] == 255);
            if (bb[j] != 255) atomicAdd(&sh[bb[j]], 1u);
        }
        uchar4 qa, qb;
        qa.x = (unsigned char)ba[0]; qa.y = (unsigned char)ba[1];
        qa.z = (unsigned char)ba[2]; qa.w = (unsigned char)ba[3];
        qb.x = (unsigned char)bb[0]; qb.y = (unsigned char)bb[1];
        qb.z = (unsigned char)bb[2]; qb.w = (unsigned char)bb[3];
        int gq0 = gq_base + ((r0 >> 7) << 4);
        int gq1 = gq_base + ((r1 >> 7) << 4);
        binsq[(size_t)gq0 * 4096 + ((r0 & 127) << 5) + qoff_c] = qa;
        binsq[(size_t)gq1 * 4096 + ((r1 & 127) << 5) + qoff_c] = qb;
    }
#pragma unroll
    for (int m = 1; m < 64; m <<= 1) hotcnt += __shfl_xor(hotcnt, m, 64);
    if (lid == 0 && hotcnt) atomicAdd(&sh[255], (unsigned)hotcnt);
    __syncthreads();

    // ---- LUT build from LDS hist (threads >=256 ride along) ----
    int wid = t >> 6;
    float h = 0.0f, ex = 0.0f;
    if (t < NBINS) {
        h = (float)sh[t];
        ex = fmaxf(h - CLIP_MAXF, 0.0f);
    }
    float s = ex;
#pragma unroll
    for (int m = 1; m < 64; m <<= 1) s += __shfl_xor(s, m, 64);
    __shared__ float wpart[8];
    if (lid == 0) wpart[wid] = s;
    __syncthreads();
    float excess = wpart[0] + wpart[1] + wpart[2] + wpart[3];

    h = fminf(h, CLIP_MAXF);
    float redist   = floorf(excess * (1.0f / 256.0f));
    float residual = excess - redist * 256.0f;
    h = h + redist + (((float)t < residual) ? 1.0f : 0.0f);

    float c = h;
#pragma unroll
    for (int m = 1; m < 64; m <<= 1) {
        float o = __shfl_up(c, m, 64);
        if (lid >= m) c += o;
    }
    __shared__ float wsum[8];
    if (lid == 63) wsum[wid] = c;
    __syncthreads();
    if (t < NBINS) {
        float off = 0.0f;
        for (int i = 0; i < wid; i++) off += wsum[i];
        c += off;
        float l = fminf(floorf(c * LUT_SCALE), 255.0f);
        l = fmaxf(l, 0.0f);
        lut[((size_t)img * NTPI + tile) * NBINS + t] = l;
    }
}

// vmax == 255 EXACTLY for any input: the input argmax pixel maps to bin 255
// (xn=1 -> t=2.5 -> clip 1 -> bin 255), every tile's lut[255]=255
// (cumsum total = 65536 -> 65536*255/65536 = 255), and v<=255 everywhere.
// So K3 is a MIN-only pass.

// ---- K3: per-quadrant v-min partials (bins read linear, quadrant-major) ----
__global__ __launch_bounds__(256, 8) void k_vmin(const uchar4* __restrict__ binsq,
                                                 const float* __restrict__ lut,
                                                 float* __restrict__ red2) {
    __shared__ float4 Lq[NBINS];
    int t = threadIdx.x;
    int qx = blockIdx.x, qy = blockIdx.y, img = blockIdx.z;
    const float* lb = lut + (size_t)img * NTPI * NBINS;
    {
        int ty2 = qy >> 1, tx2 = qx >> 1;
        int yA = (qy & 1) ? ty2 : max(ty2 - 1, 0);
        int yB = (qy & 1) ? min(ty2 + 1, GH - 1) : ty2;
        int xA = (qx & 1) ? tx2 : max(tx2 - 1, 0);
        int xB = (qx & 1) ? min(tx2 + 1, GW - 1) : tx2;
        float4 g;
        g.x = lb[(size_t)(yA * GW + xA) * NBINS + t];
        g.y = lb[(size_t)(yA * GW + xB) * NBINS + t];
        g.z = lb[(size_t)(yB * GW + xA) * NBINS + t];
        g.w = lb[(size_t)(yB * GW + xB) * NBINS + t];
        Lq[t] = g;
    }
    __syncthreads();

    int gq = (img * 16 + qy) * 16 + qx;
    const uchar4* bq = binsq + (size_t)gq * 4096;

    float vmnl = 3.4e38f;
    int gy0 = qy << 7, gx0 = qx << 7;
    int rowoff = t >> 5;  // 0..7
    int c4 = t & 31;
    int ix0 = gx0 + (c4 << 2);

    float wxv[4];
#pragma unroll
    for (int j = 0; j < 4; j++) {
        float txf = ((float)(ix0 + j) + 0.5f) * (1.0f / 256.0f) - 0.5f;
        wxv[j] = txf - floorf(txf);
    }

    for (int it = 0; it < 16; it += 2) {
        int r0 = (it << 3) + rowoff;
        int r1 = ((it + 1) << 3) + rowoff;
        uchar4 qa = bq[(r0 << 5) + c4];
        uchar4 qb = bq[(r1 << 5) + c4];
#pragma unroll
        for (int half = 0; half < 2; ++half) {
            uchar4 q = half ? qb : qa;
            int r = half ? r1 : r0;
            int iy = gy0 + r;
            int b[4] = {q.x, q.y, q.z, q.w};
            float tyf = ((float)iy + 0.5f) * (1.0f / 256.0f) - 0.5f;
            float wy = tyf - floorf(tyf);
#pragma unroll
            for (int j = 0; j < 4; j++) {
                float4 g = Lq[b[j]];
                float a = g.x + wxv[j] * (g.y - g.x);
                float bbv = g.z + wxv[j] * (g.w - g.z);
                vmnl = fminf(vmnl, a + wy * (bbv - a));
            }
        }
    }
    block_min_all<4>(vmnl, t);
    if (t == 0) red2[gq] = vmnl;
}

// ---- K4: final pass; normalize folded into Lq; NT stores to out ----
__global__ __launch_bounds__(256, 8) void k_final(const uchar4* __restrict__ binsq,
                                                  const float* __restrict__ lut,
                                                  const float* __restrict__ red2,
                                                  float4* __restrict__ out) {
    __shared__ float4 Lq[NBINS];
    int t = threadIdx.x;

    float s1, s2;
    {
        float vmn = 3.4e38f;
#pragma unroll
        for (int k = 0; k < 8; k++) vmn = fminf(vmn, red2[t + k * 256]);
        block_min_all<4>(vmn, t);
        float pmn = vmn * (1.0f / 255.0f);
        float oscale = 1.0f / (1.0f - pmn);   // pmx = 255/255 = 1 exactly
        s1 = oscale * (1.0f / 255.0f);
        s2 = -pmn * oscale;
    }

    int qx = blockIdx.x, qy = blockIdx.y, img = blockIdx.z;
    const float* lb = lut + (size_t)img * NTPI * NBINS;
    {
        int ty2 = qy >> 1, tx2 = qx >> 1;
        int yA = (qy & 1) ? ty2 : max(ty2 - 1, 0);
        int yB = (qy & 1) ? min(ty2 + 1, GH - 1) : ty2;
        int xA = (qx & 1) ? tx2 : max(tx2 - 1, 0);
        int xB = (qx & 1) ? min(tx2 + 1, GW - 1) : tx2;
        float4 g;
        g.x = lb[(size_t)(yA * GW + xA) * NBINS + t] * s1 + s2;
        g.y = lb[(size_t)(yA * GW + xB) * NBINS + t] * s1 + s2;
        g.z = lb[(size_t)(yB * GW + xA) * NBINS + t] * s1 + s2;
        g.w = lb[(size_t)(yB * GW + xB) * NBINS + t] * s1 + s2;
        Lq[t] = g;
    }
    __syncthreads();

    int gq = (img * 16 + qy) * 16 + qx;
    const uchar4* bq = binsq + (size_t)gq * 4096;

    int gy0 = qy << 7, gx0 = qx << 7;
    int rowoff = t >> 5;
    int c4 = t & 31;
    int ix0 = gx0 + (c4 << 2);

    float wxv[4];
#pragma unroll
    for (int j = 0; j < 4; j++) {
        float txf = ((float)(ix0 + j) + 0.5f) * (1.0f / 256.0f) - 0.5f;
        wxv[j] = txf - floorf(txf);
    }

    for (int it = 0; it < 16; it += 2) {
        int r0 = (it << 3) + rowoff;
        int r1 = ((it + 1) << 3) + rowoff;
        uchar4 qa = bq[(r0 << 5) + c4];
        uchar4 qb = bq[(r1 << 5) + c4];
#pragma unroll
        for (int half = 0; half < 2; ++half) {
            uchar4 q = half ? qb : qa;
            int r = half ? r1 : r0;
            int iy = gy0 + r;
            int b[4] = {q.x, q.y, q.z, q.w};
            float tyf = ((float)iy + 0.5f) * (1.0f / 256.0f) - 0.5f;
            float wy = tyf - floorf(tyf);
            float4 o;
            float* op = &o.x;
#pragma unroll
            for (int j = 0; j < 4; j++) {
                float4 g = Lq[b[j]];
                float a = g.x + wxv[j] * (g.y - g.x);
                float bbv = g.z + wxv[j] * (g.w - g.z);
                op[j] = a + wy * (bbv - a);
            }
            size_t pidx = ((size_t)img * IMH + iy) * IMW + ix0;
            f32x4 ov = {o.x, o.y, o.z, o.w};
            __builtin_nontemporal_store(ov, (f32x4*)&out[pidx >> 2]);
        }
    }
}

extern "C" void kernel_launch(void* const* d_in, const int* in_sizes, int n_in,
                              void* d_out, int out_size, void* d_ws, size_t ws_size,
                              hipStream_t stream) {
    const float* x = (const float*)d_in[0];
    float4* out = (float4*)d_out;

    unsigned char* ws = (unsigned char*)d_ws;
    float* lut    = (float*)(ws + 64);                       // 512 KB
    float2* red1  = (float2*)(ws + 64 + 512 * 1024);         // 16 KB (2048 float2)
    float* red2   = (float*)(ws + 64 + 512 * 1024 + 16384);  // 8 KB (2048 float)
    uchar4* binsq = (uchar4*)(ws + 1024 * 1024);             // 33.5 MB quadrant-major

    k_minmax_in<<<dim3(MM_BLOCKS), dim3(256), 0, stream>>>((const float4*)x, red1);
    k_hist<<<dim3(NTPI, NIMG), dim3(512), 0, stream>>>(x, red1, lut, binsq);
    dim3 qgrid(16, 16, NIMG);
    k_vmin<<<qgrid, dim3(256), 0, stream>>>(binsq, lut, red2);
    k_final<<<qgrid, dim3(256), 0, stream>>>(binsq, lut, red2, out);
}